// Round 3
// baseline (14755.768 us; speedup 1.0000x reference)
//
#include <hip/hip_runtime.h>

#define T_STEPS 4096
#define IDIM 2048
#define HDIM 2048
#define G4DIM 8192

typedef __attribute__((ext_vector_type(8))) short short8;
typedef __attribute__((ext_vector_type(4))) float f32x4;
typedef __attribute__((ext_vector_type(2))) float f32x2;

__device__ __forceinline__ unsigned short f2bf(float f) {
  unsigned int u = __float_as_uint(f);
  u += 0x7fffu + ((u >> 16) & 1u);
  return (unsigned short)(u >> 16);
}
__device__ __forceinline__ float bf2f(unsigned short h) {
  return __uint_as_float(((unsigned int)h) << 16);
}

// C[M,N] = act( sum_k A[m,k]*B[n,k] + bias[n] )
// A: fp32 [M,K] row-major; B: fp32 [N,K] row-major (i.e. B^T form).
// Split-bf16: each fp32 -> hi+lo bf16; 3 MFMA passes (hi*hi + hi*lo + lo*hi)
// gives ~fp32-level accuracy at 1/3 of bf16 MFMA rate.
template <int ACT_SIGMOID, int OUT_BF16>
__global__ __launch_bounds__(256) void gemm_bt(
    const float* __restrict__ A, const float* __restrict__ B,
    const float* __restrict__ bias, void* __restrict__ Cout,
    int M, int N, int K)
{
  // 40 = 32 + 8 pad (16B) -> row stride 80 B = 20 banks: 2-way max (free)
  __shared__ short Ah[64][40];
  __shared__ short Al[64][40];
  __shared__ short Bh[64][40];
  __shared__ short Bl[64][40];
  const int tid  = threadIdx.x;
  const int wave = tid >> 6, lane = tid & 63;
  const int bn = blockIdx.x * 64, bm = blockIdx.y * 64;
  const int srow = tid >> 2, sc8 = (tid & 3) * 8;     // staging: 64 rows x 4 chunks of 8
  const int wm = (wave >> 1) * 32, wn = (wave & 1) * 32;
  const int lq = lane >> 4, lr = lane & 15;           // quad, index-in-tile
  f32x4 acc[2][2] = {};

  for (int k0 = 0; k0 < K; k0 += 32) {
    __syncthreads();
    {   // stage A tile (64x32 fp32 -> hi/lo bf16)
      const float* src = A + (size_t)(bm + srow) * K + k0 + sc8;
      float4 v0 = *(const float4*)(src);
      float4 v1 = *(const float4*)(src + 4);
      float vv[8] = {v0.x, v0.y, v0.z, v0.w, v1.x, v1.y, v1.z, v1.w};
      short8 vh, vl;
      #pragma unroll
      for (int i = 0; i < 8; ++i) {
        unsigned short hb = f2bf(vv[i]);
        vh[i] = (short)hb;
        vl[i] = (short)f2bf(vv[i] - bf2f(hb));
      }
      *(short8*)&Ah[srow][sc8] = vh;
      *(short8*)&Al[srow][sc8] = vl;
    }
    {   // stage B tile
      const float* src = B + (size_t)(bn + srow) * K + k0 + sc8;
      float4 v0 = *(const float4*)(src);
      float4 v1 = *(const float4*)(src + 4);
      float vv[8] = {v0.x, v0.y, v0.z, v0.w, v1.x, v1.y, v1.z, v1.w};
      short8 vh, vl;
      #pragma unroll
      for (int i = 0; i < 8; ++i) {
        unsigned short hb = f2bf(vv[i]);
        vh[i] = (short)hb;
        vl[i] = (short)f2bf(vv[i] - bf2f(hb));
      }
      *(short8*)&Bh[srow][sc8] = vh;
      *(short8*)&Bl[srow][sc8] = vl;
    }
    __syncthreads();

    short8 ah0 = *(const short8*)&Ah[wm +      lr][lq * 8];
    short8 al0 = *(const short8*)&Al[wm +      lr][lq * 8];
    short8 ah1 = *(const short8*)&Ah[wm + 16 + lr][lq * 8];
    short8 al1 = *(const short8*)&Al[wm + 16 + lr][lq * 8];
    short8 bh0 = *(const short8*)&Bh[wn +      lr][lq * 8];
    short8 bl0 = *(const short8*)&Bl[wn +      lr][lq * 8];
    short8 bh1 = *(const short8*)&Bh[wn + 16 + lr][lq * 8];
    short8 bl1 = *(const short8*)&Bl[wn + 16 + lr][lq * 8];

    acc[0][0] = __builtin_amdgcn_mfma_f32_16x16x32_bf16(ah0, bh0, acc[0][0], 0, 0, 0);
    acc[0][0] = __builtin_amdgcn_mfma_f32_16x16x32_bf16(ah0, bl0, acc[0][0], 0, 0, 0);
    acc[0][0] = __builtin_amdgcn_mfma_f32_16x16x32_bf16(al0, bh0, acc[0][0], 0, 0, 0);

    acc[0][1] = __builtin_amdgcn_mfma_f32_16x16x32_bf16(ah0, bh1, acc[0][1], 0, 0, 0);
    acc[0][1] = __builtin_amdgcn_mfma_f32_16x16x32_bf16(ah0, bl1, acc[0][1], 0, 0, 0);
    acc[0][1] = __builtin_amdgcn_mfma_f32_16x16x32_bf16(al0, bh1, acc[0][1], 0, 0, 0);

    acc[1][0] = __builtin_amdgcn_mfma_f32_16x16x32_bf16(ah1, bh0, acc[1][0], 0, 0, 0);
    acc[1][0] = __builtin_amdgcn_mfma_f32_16x16x32_bf16(ah1, bl0, acc[1][0], 0, 0, 0);
    acc[1][0] = __builtin_amdgcn_mfma_f32_16x16x32_bf16(al1, bh0, acc[1][0], 0, 0, 0);

    acc[1][1] = __builtin_amdgcn_mfma_f32_16x16x32_bf16(ah1, bh1, acc[1][1], 0, 0, 0);
    acc[1][1] = __builtin_amdgcn_mfma_f32_16x16x32_bf16(ah1, bl1, acc[1][1], 0, 0, 0);
    acc[1][1] = __builtin_amdgcn_mfma_f32_16x16x32_bf16(al1, bh1, acc[1][1], 0, 0, 0);
  }

  // epilogue: D row = (lane>>4)*4 + reg, col = lane&15
  #pragma unroll
  for (int mi = 0; mi < 2; ++mi) {
    #pragma unroll
    for (int ni = 0; ni < 2; ++ni) {
      #pragma unroll
      for (int rr = 0; rr < 4; ++rr) {
        int row = bm + wm + mi * 16 + lq * 4 + rr;
        int col = bn + wn + ni * 16 + lr;
        float v = acc[mi][ni][rr];
        if (bias) v += bias[col];
        if (ACT_SIGMOID) v = 1.f / (1.f + __expf(-v));
        if (OUT_BF16)
          ((unsigned short*)Cout)[(size_t)row * N + col] = f2bf(v);
        else
          ((float*)Cout)[(size_t)row * N + col] = v;
      }
    }
  }
}

// Persistent-weight LSTM scan, v4: v2 barrier skeleton (empirically best) +
//  * 4-deep pipelined hot poll (no s_sleep): 4 relaxed 8B loads in flight,
//    check the oldest -> detection quantization ~L/4 instead of ~L. Threads
//    whose data already landed exit after 1 check, so the hot loop only runs
//    on stragglers (v3.1's regression was free-running waves + seq spin, NOT
//    poll heat on the straggler path).
//  * gx[t+1] register prefetch (kept from v3.1).
//  * transposed partials [32][17] + wave0 ds_read_b128 sums (kept).
//  * FUSED output GEMM: out[t] = sigmoid(Wo@h(t)+bo). Each WG owns 8 output
//    cols; Wo slice lives in 16 VGPR/thread. out-partials are computed
//    POST-barrier (in the >=1000cy shadow while waiting for remote h);
//    wave1 finalizes row t-2 post-barrier; wave0 does its share after the
//    h-store. Loop runs T+2 iters to drain rows T-2, T-1. Kernel 3 deleted.
// Ordering: gate-partials parity WAR gated by the global dataflow chain as
// in v2. out-partials buf p written post-barrier(t), read post-barrier(t+1),
// rewritten post-barrier(t+2) -> barrier-separated. h_lds chunks are only
// ever read by the threads that wrote them (same-thread program order).
__global__ __launch_bounds__(1024, 4) void lstm_scan(
    const float* __restrict__ Whh,
    const float* __restrict__ b_ih, const float* __restrict__ b_hh,
    const unsigned short* __restrict__ gx,   // [T][8192] bf16
    float* __restrict__ hs,                  // [T][2048] fp32, poisoned 0xAA
    const float* __restrict__ Wo,            // [2048][2048] row-major
    const float* __restrict__ bo,            // [2048]
    float* __restrict__ out)                 // [T][2048] fp32
{
  const int b    = blockIdx.x;
  const int tid  = threadIdx.x;
  const int u    = tid & 7;       // unit within WG
  const int kc   = tid >> 3;      // K-chunk [0,128)
  const int wv   = tid >> 6;      // wave [0,16)
  const int lane = tid & 63;

  // Whh weights: gate g, k in [kc*16, kc*16+16)
  f32x2 w2[4][8];
  #pragma unroll
  for (int g = 0; g < 4; ++g) {
    const float* wp = Whh + (size_t)(g * HDIM + b * 8 + u) * HDIM + kc * 16;
    #pragma unroll
    for (int i = 0; i < 4; ++i) {
      float4 v = *(const float4*)(wp + 4 * i);
      w2[g][2 * i]     = f32x2{v.x, v.y};
      w2[g][2 * i + 1] = f32x2{v.z, v.w};
    }
  }
  // Wo weights: out-row b*8+u, k in [kc*16, kc*16+16)
  f32x2 wo2[8];
  {
    const float* wop = Wo + (size_t)(b * 8 + u) * HDIM + kc * 16;
    #pragma unroll
    for (int i = 0; i < 4; ++i) {
      float4 v = *(const float4*)(wop + 4 * i);
      wo2[2 * i]     = f32x2{v.x, v.y};
      wo2[2 * i + 1] = f32x2{v.z, v.w};
    }
  }
  float bias_r = 0.f;
  if (tid < 32) {
    int br = (tid >> 3) * HDIM + b * 8 + (tid & 7);
    bias_r = b_ih[br] + b_hh[br];
  }
  float bo_r = 0.f;
  if (wv == 1 && lane < 8) bo_r = bo[b * 8 + lane];
  float cval = 0.f;  // lanes tid<8 only

  __shared__ float h_lds[128 * 20];        // padded chunks: stride 20 dwords
  __shared__ float partials[2][32][17];    // [buf][gate-row][wave], pad 17
  __shared__ float opart[2][8][17];        // [buf][out-row][wave], pad 17
  unsigned int* hs_u = (unsigned int*)hs;

  // gx prefetch registers (tid<32 only)
  const unsigned short* gxp = gx + (tid >> 3) * HDIM + b * 8 + (tid & 7);
  unsigned short gxr_cur = 0, gxr_nxt = 0;
  if (tid < 32) gxr_cur = gxp[0];

  for (int t = 0; t < T_STEPS + 2; ++t) {
    const int  buf      = t & 1;
    const bool do_gates = (t < T_STEPS);
    const bool do_hload = (t >= 1 && t <= T_STEPS);
    if (tid < 32 && t + 1 < T_STEPS)
      gxr_nxt = gxp[(size_t)(t + 1) * G4DIM];

    // ---- poll + stage h(t-1) ----
    if (do_hload) {
      const unsigned long long* p =
          (const unsigned long long*)(hs_u + (size_t)(t - 1) * HDIM + tid * 2);
      #define PLOAD() __hip_atomic_load(p, __ATOMIC_RELAXED, __HIP_MEMORY_SCOPE_AGENT)
      #define POK(x) (((unsigned int)(x) != 0xAAAAAAAAu) && \
                      ((unsigned int)((x) >> 32) != 0xAAAAAAAAu))
      unsigned long long r0 = PLOAD(), r1 = PLOAD(), r2 = PLOAD(), r3 = PLOAD();
      unsigned long long v;
      for (;;) {
        if (POK(r0)) { v = r0; break; }  r0 = PLOAD();
        if (POK(r1)) { v = r1; break; }  r1 = PLOAD();
        if (POK(r2)) { v = r2; break; }  r2 = PLOAD();
        if (POK(r3)) { v = r3; break; }  r3 = PLOAD();
      }
      #undef PLOAD
      #undef POK
      f32x2 h2w{__uint_as_float((unsigned int)v),
                __uint_as_float((unsigned int)(v >> 32))};
      *(f32x2*)&h_lds[kc * 20 + u * 2] = h2w;
    } else if (t == 0) {
      *(f32x2*)&h_lds[kc * 20 + u * 2] = f32x2{0.f, 0.f};
    }

    // ---- gate partials (pre-barrier, critical) ----
    if (do_gates) {
      f32x2 acc0{0.f, 0.f}, acc1{0.f, 0.f}, acc2{0.f, 0.f}, acc3{0.f, 0.f};
      #pragma unroll
      for (int i = 0; i < 4; ++i) {
        float4 hv = *(const float4*)&h_lds[kc * 20 + i * 4];
        f32x2 ha{hv.x, hv.y}, hb{hv.z, hv.w};
        acc0 += w2[0][2 * i] * ha;  acc0 += w2[0][2 * i + 1] * hb;
        acc1 += w2[1][2 * i] * ha;  acc1 += w2[1][2 * i + 1] * hb;
        acc2 += w2[2][2 * i] * ha;  acc2 += w2[2][2 * i + 1] * hb;
        acc3 += w2[3][2 * i] * ha;  acc3 += w2[3][2 * i + 1] * hb;
      }
      float s0 = acc0[0] + acc0[1];
      float s1 = acc1[0] + acc1[1];
      float s2 = acc2[0] + acc2[1];
      float s3 = acc3[0] + acc3[1];
      #pragma unroll
      for (int m = 8; m <= 32; m <<= 1) {
        s0 += __shfl_xor(s0, m, 64);
        s1 += __shfl_xor(s1, m, 64);
        s2 += __shfl_xor(s2, m, 64);
        s3 += __shfl_xor(s3, m, 64);
      }
      if ((tid & 56) == 0) {  // first 8 lanes of each wave
        partials[buf][0 * 8 + u][wv] = s0;
        partials[buf][1 * 8 + u][wv] = s1;
        partials[buf][2 * 8 + u][wv] = s2;
        partials[buf][3 * 8 + u][wv] = s3;
      }
    }

    __syncthreads();

    // ---- wave0: finalize gates -> h(t) (critical path) ----
    if (do_gates && tid < 64) {
      __builtin_amdgcn_s_setprio(1);
      float gval = 0.f;
      if (tid < 32) {
        float s = bf2f(gxr_cur) + bias_r;
        const float* pr = &partials[buf][tid][0];
        #pragma unroll
        for (int i = 0; i < 4; ++i) {
          float4 v = *(const float4*)(pr + 4 * i);
          s += (v.x + v.y) + (v.z + v.w);
        }
        gval = s;
      }
      float g_i = __shfl(gval, tid);
      float g_f = __shfl(gval, tid + 8);
      float g_g = __shfl(gval, tid + 16);
      float g_o = __shfl(gval, tid + 24);
      if (tid < 8) {
        float is = 1.f / (1.f + __expf(-g_i));
        float fs = 1.f / (1.f + __expf(-g_f));
        float os = 1.f / (1.f + __expf(-g_o));
        float e2 = __expf(-2.f * fabsf(g_g));
        float tg = (1.f - e2) / (1.f + e2);
        tg = (g_g < 0.f) ? -tg : tg;
        float cn = fs * cval + is * tg;
        cval = cn;
        float ec = __expf(-2.f * fabsf(cn));
        float tc = (1.f - ec) / (1.f + ec);
        tc = (cn < 0.f) ? -tc : tc;
        float hn = os * tc;
        __hip_atomic_store(hs_u + (size_t)t * HDIM + b * 8 + tid,
                           __float_as_uint(hn),
                           __ATOMIC_RELAXED, __HIP_MEMORY_SCOPE_AGENT);
      }
      __builtin_amdgcn_s_setprio(0);
    }

    // ---- out-partials for row t-1 (post-barrier: shadowed by remote-h wait)
    if (do_hload) {
      f32x2 oa{0.f, 0.f};
      #pragma unroll
      for (int i = 0; i < 4; ++i) {
        float4 hv = *(const float4*)&h_lds[kc * 20 + i * 4];
        oa += wo2[2 * i]     * f32x2{hv.x, hv.y};
        oa += wo2[2 * i + 1] * f32x2{hv.z, hv.w};
      }
      float so = oa[0] + oa[1];
      #pragma unroll
      for (int m = 8; m <= 32; m <<= 1) so += __shfl_xor(so, m, 64);
      if ((tid & 56) == 0) opart[buf][u][wv] = so;
    }

    // ---- wave1: finalize out row t-2 (shadowed) ----
    if (wv == 1 && lane < 8 && t >= 2) {
      float s = bo_r;
      const float* pr = &opart[(t - 1) & 1][lane][0];
      #pragma unroll
      for (int i = 0; i < 4; ++i) {
        float4 v = *(const float4*)(pr + 4 * i);
        s += (v.x + v.y) + (v.z + v.w);
      }
      s = 1.f / (1.f + __expf(-s));
      out[(size_t)(t - 2) * IDIM + b * 8 + lane] = s;
    }

    gxr_cur = gxr_nxt;
    // no trailing barrier: gate-partials parity WAR gated by the global
    // dataflow chain (as v2); opart parity WAR barrier-separated (see header).
  }
}

extern "C" void kernel_launch(void* const* d_in, const int* in_sizes, int n_in,
                              void* d_out, int out_size, void* d_ws, size_t ws_size,
                              hipStream_t stream) {
  (void)in_sizes; (void)n_in; (void)out_size; (void)ws_size;
  const float* x    = (const float*)d_in[0];   // [1,4096,2048]
  const float* W_ih = (const float*)d_in[1];   // [8192,2048]
  const float* W_hh = (const float*)d_in[2];   // [8192,2048]
  const float* b_ih = (const float*)d_in[3];   // [8192]
  const float* b_hh = (const float*)d_in[4];   // [8192]
  const float* Wo   = (const float*)d_in[5];   // [2048,2048]
  const float* bo   = (const float*)d_in[6];   // [2048]
  float* out = (float*)d_out;

  char* ws = (char*)d_ws;
  unsigned short* gx = (unsigned short*)ws;               // 64 MiB bf16
  float* hs = (float*)(ws + (size_t)T_STEPS * G4DIM * 2); // 32 MiB fp32

  // our own in-graph poison: the scan's dataflow sync depends on it
  hipMemsetAsync(hs, 0xAA, (size_t)T_STEPS * HDIM * sizeof(float), stream);

  // gx = x @ W_ih^T  (biases folded into the scan)
  gemm_bt<0, 1><<<dim3(G4DIM / 64, T_STEPS / 64), 256, 0, stream>>>(
      x, W_ih, nullptr, gx, T_STEPS, G4DIM, IDIM);

  // scan + fused out = sigmoid(hs @ Wo^T + bo)
  lstm_scan<<<256, 1024, 0, stream>>>(W_hh, b_ih, b_hh, gx, hs, Wo, bo, out);
}

// Round 4
// 11838.600 us; speedup vs baseline: 1.2464x; 1.2464x over previous
//
#include <hip/hip_runtime.h>

#define T_STEPS 4096
#define IDIM 2048
#define HDIM 2048
#define G4DIM 8192

typedef __attribute__((ext_vector_type(8))) short short8;
typedef __attribute__((ext_vector_type(4))) float f32x4;
typedef __attribute__((ext_vector_type(2))) float f32x2;

__device__ __forceinline__ unsigned short f2bf(float f) {
  unsigned int u = __float_as_uint(f);
  u += 0x7fffu + ((u >> 16) & 1u);
  return (unsigned short)(u >> 16);
}
__device__ __forceinline__ float bf2f(unsigned short h) {
  return __uint_as_float(((unsigned int)h) << 16);
}

// C[M,N] = act( sum_k A[m,k]*B[n,k] + bias[n] )
// A: fp32 [M,K] row-major; B: fp32 [N,K] row-major (i.e. B^T form).
// Split-bf16: each fp32 -> hi+lo bf16; 3 MFMA passes (hi*hi + hi*lo + lo*hi)
// gives ~fp32-level accuracy at 1/3 of bf16 MFMA rate.
template <int ACT_SIGMOID, int OUT_BF16>
__global__ __launch_bounds__(256) void gemm_bt(
    const float* __restrict__ A, const float* __restrict__ B,
    const float* __restrict__ bias, void* __restrict__ Cout,
    int M, int N, int K)
{
  // 40 = 32 + 8 pad (16B) -> row stride 80 B = 20 banks: 2-way max (free)
  __shared__ short Ah[64][40];
  __shared__ short Al[64][40];
  __shared__ short Bh[64][40];
  __shared__ short Bl[64][40];
  const int tid  = threadIdx.x;
  const int wave = tid >> 6, lane = tid & 63;
  const int bn = blockIdx.x * 64, bm = blockIdx.y * 64;
  const int srow = tid >> 2, sc8 = (tid & 3) * 8;     // staging: 64 rows x 4 chunks of 8
  const int wm = (wave >> 1) * 32, wn = (wave & 1) * 32;
  const int lq = lane >> 4, lr = lane & 15;           // quad, index-in-tile
  f32x4 acc[2][2] = {};

  for (int k0 = 0; k0 < K; k0 += 32) {
    __syncthreads();
    {   // stage A tile (64x32 fp32 -> hi/lo bf16)
      const float* src = A + (size_t)(bm + srow) * K + k0 + sc8;
      float4 v0 = *(const float4*)(src);
      float4 v1 = *(const float4*)(src + 4);
      float vv[8] = {v0.x, v0.y, v0.z, v0.w, v1.x, v1.y, v1.z, v1.w};
      short8 vh, vl;
      #pragma unroll
      for (int i = 0; i < 8; ++i) {
        unsigned short hb = f2bf(vv[i]);
        vh[i] = (short)hb;
        vl[i] = (short)f2bf(vv[i] - bf2f(hb));
      }
      *(short8*)&Ah[srow][sc8] = vh;
      *(short8*)&Al[srow][sc8] = vl;
    }
    {   // stage B tile
      const float* src = B + (size_t)(bn + srow) * K + k0 + sc8;
      float4 v0 = *(const float4*)(src);
      float4 v1 = *(const float4*)(src + 4);
      float vv[8] = {v0.x, v0.y, v0.z, v0.w, v1.x, v1.y, v1.z, v1.w};
      short8 vh, vl;
      #pragma unroll
      for (int i = 0; i < 8; ++i) {
        unsigned short hb = f2bf(vv[i]);
        vh[i] = (short)hb;
        vl[i] = (short)f2bf(vv[i] - bf2f(hb));
      }
      *(short8*)&Bh[srow][sc8] = vh;
      *(short8*)&Bl[srow][sc8] = vl;
    }
    __syncthreads();

    short8 ah0 = *(const short8*)&Ah[wm +      lr][lq * 8];
    short8 al0 = *(const short8*)&Al[wm +      lr][lq * 8];
    short8 ah1 = *(const short8*)&Ah[wm + 16 + lr][lq * 8];
    short8 al1 = *(const short8*)&Al[wm + 16 + lr][lq * 8];
    short8 bh0 = *(const short8*)&Bh[wn +      lr][lq * 8];
    short8 bl0 = *(const short8*)&Bl[wn +      lr][lq * 8];
    short8 bh1 = *(const short8*)&Bh[wn + 16 + lr][lq * 8];
    short8 bl1 = *(const short8*)&Bl[wn + 16 + lr][lq * 8];

    acc[0][0] = __builtin_amdgcn_mfma_f32_16x16x32_bf16(ah0, bh0, acc[0][0], 0, 0, 0);
    acc[0][0] = __builtin_amdgcn_mfma_f32_16x16x32_bf16(ah0, bl0, acc[0][0], 0, 0, 0);
    acc[0][0] = __builtin_amdgcn_mfma_f32_16x16x32_bf16(al0, bh0, acc[0][0], 0, 0, 0);

    acc[0][1] = __builtin_amdgcn_mfma_f32_16x16x32_bf16(ah0, bh1, acc[0][1], 0, 0, 0);
    acc[0][1] = __builtin_amdgcn_mfma_f32_16x16x32_bf16(ah0, bl1, acc[0][1], 0, 0, 0);
    acc[0][1] = __builtin_amdgcn_mfma_f32_16x16x32_bf16(al0, bh1, acc[0][1], 0, 0, 0);

    acc[1][0] = __builtin_amdgcn_mfma_f32_16x16x32_bf16(ah1, bh0, acc[1][0], 0, 0, 0);
    acc[1][0] = __builtin_amdgcn_mfma_f32_16x16x32_bf16(ah1, bl0, acc[1][0], 0, 0, 0);
    acc[1][0] = __builtin_amdgcn_mfma_f32_16x16x32_bf16(al1, bh0, acc[1][0], 0, 0, 0);

    acc[1][1] = __builtin_amdgcn_mfma_f32_16x16x32_bf16(ah1, bh1, acc[1][1], 0, 0, 0);
    acc[1][1] = __builtin_amdgcn_mfma_f32_16x16x32_bf16(ah1, bl1, acc[1][1], 0, 0, 0);
    acc[1][1] = __builtin_amdgcn_mfma_f32_16x16x32_bf16(al1, bh1, acc[1][1], 0, 0, 0);
  }

  // epilogue: D row = (lane>>4)*4 + reg, col = lane&15
  #pragma unroll
  for (int mi = 0; mi < 2; ++mi) {
    #pragma unroll
    for (int ni = 0; ni < 2; ++ni) {
      #pragma unroll
      for (int rr = 0; rr < 4; ++rr) {
        int row = bm + wm + mi * 16 + lq * 4 + rr;
        int col = bn + wn + ni * 16 + lr;
        float v = acc[mi][ni][rr];
        if (bias) v += bias[col];
        if (ACT_SIGMOID) v = 1.f / (1.f + __expf(-v));
        if (OUT_BF16)
          ((unsigned short*)Cout)[(size_t)row * N + col] = f2bf(v);
        else
          ((float*)Cout)[(size_t)row * N + col] = v;
      }
    }
  }
}

// Persistent-weight LSTM scan, v5 = v2 skeleton (empirically best: s_sleep
// backoff poll + per-step __syncthreads + separate out-GEMM) + critical-path
// micro-opts only. Evidence from v3.1/v4: ANY added issue pressure in the
// wait window (hot polls, free-running waves, seq spins, post-barrier VALU
// work) slows the pace; so v5 strictly REMOVES instructions from the chain:
//  * poll = single 8B relaxed atomic load per round (one vmcnt wait, not
//    two); both halves poison-checked so no store-atomicity assumption.
//  * gx[t+1] prefetched into a register a FULL step early (v2 issued it at
//    step-top where the poll's vmcnt drain could stall on its L3/HBM miss).
//  * partials transposed [32][18]: wave0 sums via 8x ds_read_b64, stride 18
//    dwords (gcd(18,32)=2 -> 2-way bank alias = free) vs 16x ds_read_b32.
//  * s_setprio(1) around wave0's finalize only (role-split: other waves are
//    in s_sleep backoff, wave0 is the global producer).
// Sync/ordering identical to v2: consumers spin on 0xAA poison in hs[t-1]
// (memset in-graph); per-step addresses never reused -> no WAR; partials
// double-buffered, parity WAR gated by the global dataflow chain.
__global__ __launch_bounds__(1024, 4) void lstm_scan(
    const float* __restrict__ Whh,
    const float* __restrict__ b_ih, const float* __restrict__ b_hh,
    const unsigned short* __restrict__ gx,   // [T][8192] bf16
    float* __restrict__ hs)                  // [T][2048] fp32, poisoned 0xAA
{
  const int b   = blockIdx.x;
  const int tid = threadIdx.x;
  const int u   = tid & 7;       // unit within WG
  const int kc  = tid >> 3;      // K-chunk [0,128)
  const int wv  = tid >> 6;      // wave [0,16)

  // weights: gate g, k in [kc*16, kc*16+16)
  f32x2 w2[4][8];
  #pragma unroll
  for (int g = 0; g < 4; ++g) {
    const float* wp = Whh + (size_t)(g * HDIM + b * 8 + u) * HDIM + kc * 16;
    #pragma unroll
    for (int i = 0; i < 4; ++i) {
      float4 v = *(const float4*)(wp + 4 * i);
      w2[g][2 * i]     = f32x2{v.x, v.y};
      w2[g][2 * i + 1] = f32x2{v.z, v.w};
    }
  }
  float bias_r = 0.f;
  if (tid < 32) {
    int br = (tid >> 3) * HDIM + b * 8 + (tid & 7);
    bias_r = b_ih[br] + b_hh[br];
  }
  float cval = 0.f;  // lanes tid<8 only

  __shared__ float h_lds[128 * 20];        // padded chunks: stride 20 dwords
  __shared__ float partials[2][32][18];    // [buf][gate-row][wave], stride 18
  unsigned int* hs_u = (unsigned int*)hs;

  // gx prefetch registers (tid<32 only); raw ushort so the vmcnt wait lands
  // at the (t+1) finalize use, a full step after issue.
  const unsigned short* gxp = gx + (tid >> 3) * HDIM + b * 8 + (tid & 7);
  unsigned short gxr_cur = 0, gxr_nxt = 0;
  if (tid < 32) gxr_cur = gxp[0];

  for (int t = 0; t < T_STEPS; ++t) {
    const int buf = t & 1;
    if (tid < 32 && t + 1 < T_STEPS)
      gxr_nxt = gxp[(size_t)(t + 1) * G4DIM];

    // poll + load this thread's 2 h elements (global idx g0 = tid*2).
    // Single aligned 8B relaxed atomic load per round; first check has no
    // sleep, stragglers back off with s_sleep(1) (v2's empirically-best
    // throttle -- keeps probe issue pressure off the producers).
    f32x2 h2w;
    if (t > 0) {
      const unsigned long long* p =
          (const unsigned long long*)(hs_u + (size_t)(t - 1) * HDIM + tid * 2);
      for (;;) {
        unsigned long long v =
            __hip_atomic_load(p, __ATOMIC_RELAXED, __HIP_MEMORY_SCOPE_AGENT);
        unsigned int lo = (unsigned int)v, hi = (unsigned int)(v >> 32);
        if (lo != 0xAAAAAAAAu && hi != 0xAAAAAAAAu) {
          h2w = f32x2{__uint_as_float(lo), __uint_as_float(hi)};
          break;
        }
        __builtin_amdgcn_s_sleep(1);
      }
    } else {
      h2w = f32x2{0.f, 0.f};
    }

    // stage into padded LDS; consumers of chunk kc are the 8 lanes that wrote
    // it (same wave) -> per-wave in-order DS pipe, no barrier needed.
    *(f32x2*)&h_lds[kc * 20 + u * 2] = h2w;

    f32x2 acc0{0.f, 0.f}, acc1{0.f, 0.f}, acc2{0.f, 0.f}, acc3{0.f, 0.f};
    #pragma unroll
    for (int i = 0; i < 4; ++i) {
      float4 hv = *(const float4*)&h_lds[kc * 20 + i * 4];
      f32x2 ha{hv.x, hv.y}, hb{hv.z, hv.w};
      acc0 += w2[0][2 * i] * ha;  acc0 += w2[0][2 * i + 1] * hb;
      acc1 += w2[1][2 * i] * ha;  acc1 += w2[1][2 * i + 1] * hb;
      acc2 += w2[2][2 * i] * ha;  acc2 += w2[2][2 * i + 1] * hb;
      acc3 += w2[3][2 * i] * ha;  acc3 += w2[3][2 * i + 1] * hb;
    }
    float s0 = acc0[0] + acc0[1];
    float s1 = acc1[0] + acc1[1];
    float s2 = acc2[0] + acc2[1];
    float s3 = acc3[0] + acc3[1];
    // fold the 8 K-chunks held by lanes {.., +8, .., +56} of this wave
    #pragma unroll
    for (int m = 8; m <= 32; m <<= 1) {
      s0 += __shfl_xor(s0, m, 64);
      s1 += __shfl_xor(s1, m, 64);
      s2 += __shfl_xor(s2, m, 64);
      s3 += __shfl_xor(s3, m, 64);
    }
    if ((tid & 56) == 0) {  // first 8 lanes of each wave
      // transposed store: row = gate-row, col = wave. Bank = (row*18+wv)%32;
      // for u=0..7 at fixed g: u*18%32 = {0,18,4,22,8,26,12,30} distinct.
      partials[buf][0 * 8 + u][wv] = s0;
      partials[buf][1 * 8 + u][wv] = s1;
      partials[buf][2 * 8 + u][wv] = s2;
      partials[buf][3 * 8 + u][wv] = s3;
    }
    __syncthreads();

    if (tid < 64) {  // wave 0 reduces + finalizes
      __builtin_amdgcn_s_setprio(1);
      float gval = 0.f;
      if (tid < 32) {
        float s = bf2f(gxr_cur) + bias_r;
        // 8x ds_read_b64 at row stride 18 dwords (72B): lane tid reads row
        // tid; bank = (tid*18 + 2i)%32, 2-way alias only (free).
        const float* pr = &partials[buf][tid][0];
        #pragma unroll
        for (int i = 0; i < 8; ++i) {
          float2 v = *(const float2*)(pr + 2 * i);
          s += v.x + v.y;
        }
        gval = s;
      }
      float g_i = __shfl(gval, tid);
      float g_f = __shfl(gval, tid + 8);
      float g_g = __shfl(gval, tid + 16);
      float g_o = __shfl(gval, tid + 24);
      if (tid < 8) {
        float is = 1.f / (1.f + __expf(-g_i));
        float fs = 1.f / (1.f + __expf(-g_f));
        float os = 1.f / (1.f + __expf(-g_o));
        float e2 = __expf(-2.f * fabsf(g_g));
        float tg = (1.f - e2) / (1.f + e2);
        tg = (g_g < 0.f) ? -tg : tg;
        float cn = fs * cval + is * tg;
        cval = cn;
        float ec = __expf(-2.f * fabsf(cn));
        float tc = (1.f - ec) / (1.f + ec);
        tc = (cn < 0.f) ? -tc : tc;
        float hn = os * tc;
        __hip_atomic_store(hs_u + (size_t)t * HDIM + b * 8 + tid,
                           __float_as_uint(hn),
                           __ATOMIC_RELAXED, __HIP_MEMORY_SCOPE_AGENT);
      }
      __builtin_amdgcn_s_setprio(0);
    }
    gxr_cur = gxr_nxt;
    // no trailing barrier: partials double-buffered; step t+2's writes are
    // gated by the global dataflow chain (our wave0's partials-read at t
    // happens-before its h(t) store -> producers' h(t+1) -> t+2 polls).
  }
}

extern "C" void kernel_launch(void* const* d_in, const int* in_sizes, int n_in,
                              void* d_out, int out_size, void* d_ws, size_t ws_size,
                              hipStream_t stream) {
  (void)in_sizes; (void)n_in; (void)out_size; (void)ws_size;
  const float* x    = (const float*)d_in[0];   // [1,4096,2048]
  const float* W_ih = (const float*)d_in[1];   // [8192,2048]
  const float* W_hh = (const float*)d_in[2];   // [8192,2048]
  const float* b_ih = (const float*)d_in[3];   // [8192]
  const float* b_hh = (const float*)d_in[4];   // [8192]
  const float* Wo   = (const float*)d_in[5];   // [2048,2048]
  const float* bo   = (const float*)d_in[6];   // [2048]
  float* out = (float*)d_out;

  char* ws = (char*)d_ws;
  unsigned short* gx = (unsigned short*)ws;               // 64 MiB bf16
  float* hs = (float*)(ws + (size_t)T_STEPS * G4DIM * 2); // 32 MiB fp32

  // our own in-graph poison: the scan's dataflow sync depends on it
  hipMemsetAsync(hs, 0xAA, (size_t)T_STEPS * HDIM * sizeof(float), stream);

  // gx = x @ W_ih^T  (biases folded into the scan)
  gemm_bt<0, 1><<<dim3(G4DIM / 64, T_STEPS / 64), 256, 0, stream>>>(
      x, W_ih, nullptr, gx, T_STEPS, G4DIM, IDIM);

  lstm_scan<<<256, 1024, 0, stream>>>(W_hh, b_ih, b_hh, gx, hs);

  // out = sigmoid(hs @ Wo^T + bo)
  gemm_bt<1, 0><<<dim3(IDIM / 64, T_STEPS / 64), 256, 0, stream>>>(
      hs, Wo, bo, out, T_STEPS, IDIM, HDIM);
}